// Round 13
// baseline (171.097 us; speedup 1.0000x reference)
//
#include <hip/hip_runtime.h>

#define BATCH 32
#define H 512
#define W 512
#define PADR 4
#define WIN 9
#define SEG 16                      // output rows per block
#define COLS 4                      // output columns per thread
#define NT 128                      // 2 waves: 128 x 4 = 512 cols
#define NSTEP (SEG + WIN - 1)       // 24 row-steps, fully unrolled
// final scalar = sum over pixels of ((1-cc1)+(1-cc2)) * 0.5 / (B*H*W)
#define SCALE (0.5f / 8388608.0f)

typedef float v4f __attribute__((ext_vector_type(4)));

// Round 13: minimal-logical-traffic kernel.
// 12-round synthesis: per-CU vector-load return path caps at ~10 B/cyc
// (~6 TB/s chip) regardless of cache level; R10/R12 were pinned on it at
// 2.9x-unique logical bytes (incoming + outgoing reload).  This round:
// 1.5x-unique only (register ring, NO reload; R2's load pattern) + DPP
// horizontal exchange (R7/R10's verified emit; at COLS=4 the 9-window
// spans exactly +-1 lane).  The wave seam t63<->t64 exchanges 8 floats/q
// via a 512B LDS slot + ONE barrier per emit (2 lockstep waves, cheap --
// nothing like R2's full-row 32-DS-op exchange).

__device__ __forceinline__ float from_left(float v) {   // lane i <- i-1; lane 0 <- 0
    return __builtin_bit_cast(float, __builtin_amdgcn_update_dpp(
        0, __builtin_bit_cast(int, v), 0x138, 0xF, 0xF, true)); // wave_shr:1
}
__device__ __forceinline__ float from_right(float v) {  // lane i <- i+1; lane 63 <- 0
    return __builtin_bit_cast(float, __builtin_amdgcn_update_dpp(
        0, __builtin_bit_cast(int, v), 0x130, 0xF, 0xF, true)); // wave_shl:1
}

__global__ __launch_bounds__(NT, 1) void ncc_loss_kernel(
    const float* __restrict__ g1, const float* __restrict__ g2,
    const float* __restrict__ gf, float* __restrict__ out)
{
    const int t  = threadIdx.x;              // 0..127
    const int x0 = t * COLS;                 // 0,4,...,508
    const int y0 = blockIdx.y * SEG;
    const int b  = blockIdx.z;
    const size_t base = (size_t)b * (size_t)(H * W);
    const int voff = x0 * 4;

    // Seam exchange (t63 <-> t64 only), double-buffered by emit parity.
    // seamL[p][q] = t63's (T, T-p1, T-p2, T-p3); seamR[p][q] = t64's (p1,p2,p3,T).
    __shared__ v4f seamL[2][8], seamR[2][8];             // 512 B

    // Incoming row, A/B step parity: 1 v4f per image per thread.
    v4f nA[3], nB[3];
    auto issue3 = [&](int yr, v4f* dst) {
        const int rec = ((unsigned)yr < (unsigned)H) ? (W * 4) : 0; // OOB row -> 0
        const int yc  = yr < 0 ? 0 : (yr >= H ? H - 1 : yr);        // safe base
        const size_t roff = base + (size_t)yc * W;                  // block-uniform
        __amdgpu_buffer_rsrc_t r1 = __builtin_amdgcn_make_buffer_rsrc(
            (void*)(g1 + roff), (short)0, rec, 0x00020000);
        __amdgpu_buffer_rsrc_t r2 = __builtin_amdgcn_make_buffer_rsrc(
            (void*)(g2 + roff), (short)0, rec, 0x00020000);
        __amdgpu_buffer_rsrc_t rf = __builtin_amdgcn_make_buffer_rsrc(
            (void*)(gf + roff), (short)0, rec, 0x00020000);
        dst[0] = __builtin_bit_cast(v4f,
            __builtin_amdgcn_raw_buffer_load_b128(r1, voff, 0, 0));
        dst[1] = __builtin_bit_cast(v4f,
            __builtin_amdgcn_raw_buffer_load_b128(r2, voff, 0, 0));
        dst[2] = __builtin_bit_cast(v4f,
            __builtin_amdgcn_raw_buffer_load_b128(rf, voff, 0, 0));
    };

    // Raw-pixel vertical ring (compile-time indices after full unroll).
    // Pre-zeroed: steps s<9 subtract 0 = zero-pad warmup (R2-verified math).
    float ring[3][WIN][COLS];
#pragma unroll
    for (int im = 0; im < 3; ++im)
#pragma unroll
        for (int i = 0; i < WIN; ++i)
#pragma unroll
            for (int c = 0; c < COLS; ++c) ring[im][i][c] = 0.f;

    // Vertical running box-sums: q = {A, C, F, AA, CC, FF, AF, CF}.
    float V[8][COLS];
#pragma unroll
    for (int q = 0; q < 8; ++q)
#pragma unroll
        for (int c = 0; c < COLS; ++c) V[q][c] = 0.f;

    float lsum = 0.f;
    const float inv_n = 1.0f / 81.0f;

    issue3(y0 - PADR + 0, nA);               // prologue prefetch
    issue3(y0 - PADR + 1, nB);

#pragma unroll
    for (int s = 0; s < NSTEP; ++s) {
        v4f* nb = (s & 1) ? nB : nA;         // compile-time select
        const int ph = s % WIN;              // compile-time

        // vertical sliding update: V += new - ring[ph]; ring[ph] = new
#pragma unroll
        for (int c = 0; c < COLS; ++c) {
            const float n1 = nb[0][c], n2 = nb[1][c], nf = nb[2][c];
            const float o1 = ring[0][ph][c], o2 = ring[1][ph][c],
                        of = ring[2][ph][c];
            V[0][c] += n1 - o1;
            V[1][c] += n2 - o2;
            V[2][c] += nf - of;
            V[3][c] = fmaf(n1, n1, fmaf(-o1, o1, V[3][c]));
            V[4][c] = fmaf(n2, n2, fmaf(-o2, o2, V[4][c]));
            V[5][c] = fmaf(nf, nf, fmaf(-of, of, V[5][c]));
            V[6][c] = fmaf(n1, nf, fmaf(-o1, of, V[6][c]));
            V[7][c] = fmaf(n2, nf, fmaf(-o2, of, V[7][c]));
            ring[0][ph][c] = n1; ring[1][ph][c] = n2; ring[2][ph][c] = nf;
        }

        if (s + 2 < NSTEP) issue3(y0 - PADR + s + 2, nb);   // refill (latency
                                                            // hides under emit)
        if (s >= WIN - 1) {                  // emit output row y0 + s - 8
            const int par = s & 1;           // compile-time

            // per-q prefixes of the 4 own columns: p1, p2, p3, T
            float P[8][4];
#pragma unroll
            for (int q = 0; q < 8; ++q) {
                const float p1 = V[q][0];
                const float p2 = p1 + V[q][1];
                const float p3 = p2 + V[q][2];
                const float T  = p3 + V[q][3];
                P[q][0] = p1; P[q][1] = p2; P[q][2] = p3; P[q][3] = T;
                if (t == 63) {               // left side of the wave seam
                    v4f v; v.x = T; v.y = T - p1; v.z = T - p2; v.w = T - p3;
                    seamL[par][q] = v;
                }
                if (t == 64) {               // right side of the wave seam
                    v4f v; v.x = p1; v.y = p2; v.z = p3; v.w = T;
                    seamR[par][q] = v;
                }
            }
            __syncthreads();                 // seam packs visible cross-wave

            // window sums: S[j] = Lsuf(4-j) + T + Rpre(j+1)
            float S[8][4];
#pragma unroll
            for (int q = 0; q < 8; ++q) {
                const float T  = P[q][3];
                const float a0 = T;
                const float a1 = T - P[q][0];
                const float a2 = T - P[q][1];
                const float a3 = T - P[q][2];
                float l0 = from_left(a0), l1 = from_left(a1),
                      l2 = from_left(a2), l3 = from_left(a3);
                float r0 = from_right(P[q][0]), r1 = from_right(P[q][1]),
                      r2 = from_right(P[q][2]), r3 = from_right(P[q][3]);
                const v4f sl = seamL[par][q];
                const v4f sr = seamR[par][q];
                // DPP gave 0 at lane 0/63 of each wave; fix the block-interior
                // seam (t==64 left side, t==63 right side) from LDS.
                l0 = (t == 64) ? sl.x : l0;  l1 = (t == 64) ? sl.y : l1;
                l2 = (t == 64) ? sl.z : l2;  l3 = (t == 64) ? sl.w : l3;
                r0 = (t == 63) ? sr.x : r0;  r1 = (t == 63) ? sr.y : r1;
                r2 = (t == 63) ? sr.z : r2;  r3 = (t == 63) ? sr.w : r3;
                S[q][0] = (l0 + T) + r0;
                S[q][1] = (l1 + T) + r1;
                S[q][2] = (l2 + T) + r2;
                S[q][3] = (l3 + T) + r3;
            }

            // NCC epilogue per column
#pragma unroll
            for (int c = 0; c < COLS; ++c) {
                const float sA = S[0][c], sC = S[1][c], sF = S[2][c];
                const float u1 = sA * inv_n;
                const float u2 = sC * inv_n;
                const float uf = sF * inv_n;
                const float cross1 = fmaf(-sA, uf, S[6][c]);
                const float var1   = fmaf(-sA, u1, S[3][c]);
                const float varf   = fmaf(-sF, uf, S[5][c]);
                const float cross2 = fmaf(-sC, uf, S[7][c]);
                const float var2   = fmaf(-sC, u2, S[4][c]);
                const float d1 = fmaf(var1, varf, 1e-5f);
                const float d2 = fmaf(var2, varf, 1e-5f);
                // cc1 + cc2 = (cross1^2*d2 + cross2^2*d1)/(d1*d2): single rcp
                const float inv = __builtin_amdgcn_rcpf(d1 * d2);
                float num = cross1 * cross1 * d2;
                num = fmaf(cross2 * cross2, d1, num);
                lsum += fmaf(-num, inv, 2.0f);   // (1-cc1)+(1-cc2)
            }
        }
    }

    // block reduction: wave shuffle -> LDS -> one atomic per block
#pragma unroll
    for (int offd = 32; offd > 0; offd >>= 1)
        lsum += __shfl_down(lsum, offd);
    __shared__ float wsum[2];
    const int lane = t & 63;
    const int wid  = t >> 6;
    if (lane == 0) wsum[wid] = lsum;
    __syncthreads();
    if (t == 0) atomicAdd(out, (wsum[0] + wsum[1]) * SCALE);
}

extern "C" void kernel_launch(void* const* d_in, const int* in_sizes, int n_in,
                              void* d_out, int out_size, void* d_ws, size_t ws_size,
                              hipStream_t stream) {
    const float* img1 = (const float*)d_in[0];
    const float* img2 = (const float*)d_in[1];
    const float* fimg = (const float*)d_in[2];
    float* out = (float*)d_out;

    hipMemsetAsync(out, 0, sizeof(float), stream);  // d_out re-poisoned each call

    dim3 grid(1, H / SEG, BATCH);        // (1, 32, 32) = 1024 blocks
    ncc_loss_kernel<<<grid, dim3(NT), 0, stream>>>(img1, img2, fimg, out);
}